// Round 3
// baseline (946.928 us; speedup 1.0000x reference)
//
#include <hip/hip_runtime.h>

// FixedConv1DPriorEnsemble: DZ=30 ensemble of conv nets over embedded tokens.
// V=32000 E=8 DZ=30 C=10, CH=(4,8,8), K=3, S=(2,2,1), B=512, L=4096.
// L1=2047, L2=1023, L3=1021. Output [512,10] fp32.
//
// One block per (b, d). R2 lessons:
//  - VGPR weight arrays get rematerialized as per-FMA ds_reads (VGPR=112).
//    Fix: weights are BLOCK-UNIFORM -> force into SGPRs (readfirstlane on
//    uniform global loads -> s_load). v_fma reads 1 SGPR operand free.
//    Loop over input channel keeps <=24 weight SGPRs live.
//  - Consecutive-4 blocking made lane-stride-4/8 LDS (26M conflict cycles).
//    Fix: scattered outputs j = tid + k*256 -> lane-stride 1-2 (conflict-free).
//  - h2 overlays h1 (stage-2 outputs buffered in regs across a barrier):
//    33 KB LDS -> 4 blocks/CU with __launch_bounds__(256,4).

#define L1_ 2047
#define L2_ 1023
#define L3_ 1021

__device__ __forceinline__ float ufl(float x) {   // force block-uniform -> SGPR
  return __int_as_float(__builtin_amdgcn_readfirstlane(__float_as_int(x)));
}

__global__ void zero_out_kernel(float* __restrict__ out, int n) {
  int i = blockIdx.x * blockDim.x + threadIdx.x;
  if (i < n) out[i] = 0.0f;
}

__global__ __launch_bounds__(256, 4) void ensemble_kernel(
    const int* __restrict__ ids,      // [512][4096]
    const float* __restrict__ mask,   // [512][4096]
    const float* __restrict__ z,      // [30]
    const float* __restrict__ tbl,    // [32000][8]
    const float* __restrict__ W1, const float* __restrict__ b1,   // [30][4][8][3], [30][4]
    const float* __restrict__ W2, const float* __restrict__ b2,   // [30][8][4][3], [30][8]
    const float* __restrict__ W3, const float* __restrict__ b3,   // [30][8][8][3], [30][8]
    const float* __restrict__ Wh, const float* __restrict__ bh,   // [30][10][8], [30][10]
    float* __restrict__ out)          // [512][10]
{
  const int tid = threadIdx.x;
  const int b = blockIdx.x & 511;   // grid = 512*30
  const int d = blockIdx.x >> 9;

  // h1 [4][2048] lives here during stages 1-2; h2 [8][1024] overlays it for stage 3.
  __shared__ float smem[8192 + 16];
  __shared__ float red[32];
  __shared__ float pooled[8];

  const int*    idrow = ids  + (size_t)b * 4096;
  const float*  mrow  = mask + (size_t)b * 4096;
  const float4* tbl4  = (const float4*)tbl;     // table row = 2x float4
  const float*  w1p = W1 + d * 96;
  const float*  w2p = W2 + d * 96;
  const float*  w3p = W3 + d * 192;

  // ---- stage 1: conv1 (E=8 -> 4ch, K=3, stride 2). 2 outputs/thread x 4 passes. ----
  #pragma unroll 1
  for (int pp = 0; pp < 4; ++pp) {
    const int l0 = pp * 512 + tid * 2;          // outputs l0, l0+1
    const int p0 = 2 * l0;                      // input positions p0..p0+4 (p0 % 4 == 0)
    const int4   iv = *(const int4*)(idrow + p0);
    const float4 mv = *(const float4*)(mrow + p0);
    int i4; float m4;
    if (p0 + 4 < 4096) { i4 = idrow[p0 + 4]; m4 = mrow[p0 + 4]; }
    else               { i4 = 0;              m4 = 0.0f; }

    const int   pid[5] = {iv.x, iv.y, iv.z, iv.w, i4};
    const float pm[5]  = {mv.x, mv.y, mv.z, mv.w, m4};
    float xv[5][8];
    #pragma unroll
    for (int q = 0; q < 5; ++q) {
      const float4 a = tbl4[(size_t)pid[q] * 2];
      const float4 c = tbl4[(size_t)pid[q] * 2 + 1];
      xv[q][0] = a.x * pm[q]; xv[q][1] = a.y * pm[q];
      xv[q][2] = a.z * pm[q]; xv[q][3] = a.w * pm[q];
      xv[q][4] = c.x * pm[q]; xv[q][5] = c.y * pm[q];
      xv[q][6] = c.z * pm[q]; xv[q][7] = c.w * pm[q];
    }

    float acc[4][2];
    #pragma unroll
    for (int c = 0; c < 4; ++c) {
      const float bb = ufl(b1[d * 4 + c]);
      acc[c][0] = bb; acc[c][1] = bb;
    }
    #pragma unroll 2
    for (int e = 0; e < 8; ++e) {
      #pragma unroll
      for (int c = 0; c < 4; ++c) {
        #pragma unroll
        for (int k = 0; k < 3; ++k) {
          const float w = ufl(w1p[c * 24 + e * 3 + k]);   // SGPR weight
          acc[c][0] += xv[k][e]     * w;
          acc[c][1] += xv[2 + k][e] * w;
        }
      }
    }
    if (l0 + 1 < L1_) {          // lane-stride-2 float2 writes: conflict-free
      #pragma unroll
      for (int c = 0; c < 4; ++c)
        *(float2*)(smem + c * 2048 + l0) =
            make_float2(fmaxf(acc[c][0], 0.0f), fmaxf(acc[c][1], 0.0f));
    } else {                     // only (pp==3, tid==255): l0==2046
      #pragma unroll
      for (int c = 0; c < 4; ++c)
        smem[c * 2048 + l0] = fmaxf(acc[c][0], 0.0f);
    }
  }
  __syncthreads();

  // ---- stage 2: conv2 (4 -> 8ch, K=3, stride 2). outputs j = tid + k*256. ----
  float o2[8][4];
  {
    float acc2[8][4];
    #pragma unroll
    for (int c2 = 0; c2 < 8; ++c2) {
      const float bb = ufl(b2[d * 8 + c2]);
      #pragma unroll
      for (int k = 0; k < 4; ++k) acc2[c2][k] = bb;
    }
    #pragma unroll 1
    for (int c1 = 0; c1 < 4; ++c1) {
      float sw[8][3];                         // 24 SGPR weights live
      #pragma unroll
      for (int c2 = 0; c2 < 8; ++c2)
        #pragma unroll
        for (int kk = 0; kk < 3; ++kk)
          sw[c2][kk] = ufl(w2p[c2 * 12 + c1 * 3 + kk]);
      #pragma unroll
      for (int k = 0; k < 4; ++k) {
        const int j = tid + k * 256;          // j==1023 computed, never stored
        const float* hp = smem + c1 * 2048 + 2 * j;   // lane-stride 2: conflict-free
        const float h0 = hp[0], h1v = hp[1], h2v = hp[2];
        #pragma unroll
        for (int c2 = 0; c2 < 8; ++c2)
          acc2[c2][k] += h0 * sw[c2][0] + h1v * sw[c2][1] + h2v * sw[c2][2];
      }
    }
    #pragma unroll
    for (int c2 = 0; c2 < 8; ++c2)
      #pragma unroll
      for (int k = 0; k < 4; ++k) o2[c2][k] = fmaxf(acc2[c2][k], 0.0f);
  }
  __syncthreads();               // all h1 reads done; safe to overlay h2
  #pragma unroll
  for (int k = 0; k < 4; ++k) {
    const int j = tid + k * 256;
    if (j < L2_) {
      #pragma unroll
      for (int c2 = 0; c2 < 8; ++c2)
        smem[c2 * 1024 + j] = o2[c2][k];      // lane-stride 1: conflict-free
    }
  }
  __syncthreads();

  // ---- stage 3: conv3 (8 -> 8ch, K=3, stride 1) + relu + pool. i = tid + k*256. ----
  float acc3[8][4];
  #pragma unroll
  for (int cc = 0; cc < 8; ++cc) {
    const float bb = ufl(b3[d * 8 + cc]);
    #pragma unroll
    for (int k = 0; k < 4; ++k) acc3[cc][k] = bb;
  }
  #pragma unroll 1
  for (int c2 = 0; c2 < 8; ++c2) {
    float sw[8][3];                           // 24 SGPR weights live
    #pragma unroll
    for (int cc = 0; cc < 8; ++cc)
      #pragma unroll
      for (int kk = 0; kk < 3; ++kk)
        sw[cc][kk] = ufl(w3p[cc * 24 + c2 * 3 + kk]);
    #pragma unroll
    for (int k = 0; k < 4; ++k) {
      const int i = tid + k * 256;            // i>=1021 computed, masked in pool
      const float* hp = smem + c2 * 1024 + i; // lane-stride 1: conflict-free
      const float h0 = hp[0], h1v = hp[1], h2v = hp[2];
      #pragma unroll
      for (int cc = 0; cc < 8; ++cc)
        acc3[cc][k] += h0 * sw[cc][0] + h1v * sw[cc][1] + h2v * sw[cc][2];
    }
  }
  float psum[8];
  #pragma unroll
  for (int cc = 0; cc < 8; ++cc) {
    float s = 0.0f;
    #pragma unroll
    for (int k = 0; k < 4; ++k)
      if (tid + k * 256 < L3_) s += fmaxf(acc3[cc][k], 0.0f);
    psum[cc] = s;
  }

  // ---- block reduction of pooled sums ----
  const int lane = tid & 63;
  const int wid  = tid >> 6;
  #pragma unroll
  for (int c = 0; c < 8; ++c) {
    float v = psum[c];
    #pragma unroll
    for (int off = 32; off > 0; off >>= 1) v += __shfl_down(v, off, 64);
    if (lane == 0) red[wid * 8 + c] = v;
  }
  __syncthreads();
  if (tid < 8)
    pooled[tid] = red[tid] + red[8 + tid] + red[16 + tid] + red[24 + tid];
  __syncthreads();

  // ---- head: out[b][c] += z[d] * (mean(pooled) @ Wh^T + bh) ----
  if (tid < 10) {
    float acc = bh[d * 10 + tid];
    #pragma unroll
    for (int c3 = 0; c3 < 8; ++c3)
      acc += pooled[c3] * (1.0f / 1021.0f) * Wh[d * 80 + tid * 8 + c3];
    atomicAdd(&out[b * 10 + tid], z[d] * acc);
  }
}

extern "C" void kernel_launch(void* const* d_in, const int* in_sizes, int n_in,
                              void* d_out, int out_size, void* d_ws, size_t ws_size,
                              hipStream_t stream) {
  const int*   ids  = (const int*)d_in[0];
  const float* mask = (const float*)d_in[1];
  const float* z    = (const float*)d_in[2];
  const float* tbl  = (const float*)d_in[3];
  const float* W1   = (const float*)d_in[4];
  const float* b1   = (const float*)d_in[5];
  const float* W2   = (const float*)d_in[6];
  const float* b2   = (const float*)d_in[7];
  const float* W3   = (const float*)d_in[8];
  const float* b3   = (const float*)d_in[9];
  const float* Wh   = (const float*)d_in[10];
  const float* bh   = (const float*)d_in[11];
  float* out = (float*)d_out;

  hipLaunchKernelGGL(zero_out_kernel, dim3(20), dim3(256), 0, stream, out, 5120);
  hipLaunchKernelGGL(ensemble_kernel, dim3(512 * 30), dim3(256), 0, stream,
                     ids, mask, z, tbl, W1, b1, W2, b2, W3, b3, Wh, bh, out);
}

// Round 5
// 424.329 us; speedup vs baseline: 2.2316x; 2.2316x over previous
//
#include <hip/hip_runtime.h>

// FixedConv1DPriorEnsemble: DZ=30 ensemble of conv nets over embedded tokens.
// V=32000 E=8 DZ=30 C=10, CH=(4,8,8), K=3, S=(2,2,1), B=512, L=4096.
// L1=2047, L2=1023, L3=1021. Output [512,10] fp32.
//
// One block per (b, d). History:
//  R1: weights "in registers" -> rematerialized as per-FMA ds_reads. 585us.
//  R2: consecutive-4 blocking -> lane-stride-4 LDS, 26M conflict cyc. 585us.
//  R3: partial unroll left runtime index into reg array -> scratch spill. 947us.
//  R4: full unroll + SGPR weights + paired LDS: 444us BUT post-timing output
//      diverged across calls (atomic-order nondeterminism / uninit-LDS class).
//  R5: determinism fixes, zero perf-structure change:
//      - NO atomics: partials to d_ws[d][b][c], fixed-order reduce kernel
//        overwrites d_out (poison-immune, bitwise-deterministic).
//      - zero the never-written LDS tail slots (h1[c][2047], h2[c][1023], pad).

#define L1_ 2047
#define L2_ 1023
#define L3_ 1021

__global__ __launch_bounds__(256, 4) void ensemble_kernel(
    const int* __restrict__ ids,      // [512][4096]
    const float* __restrict__ mask,   // [512][4096]
    const float* __restrict__ z,      // [30]
    const float* __restrict__ tbl,    // [32000][8]
    const float* __restrict__ W1, const float* __restrict__ b1,   // [30][4][8][3], [30][4]
    const float* __restrict__ W2, const float* __restrict__ b2,   // [30][8][4][3], [30][8]
    const float* __restrict__ W3, const float* __restrict__ b3,   // [30][8][8][3], [30][8]
    const float* __restrict__ Wh, const float* __restrict__ bh,   // [30][10][8], [30][10]
    float* __restrict__ part)         // [30][512][10] partials in d_ws
{
  const int tid = threadIdx.x;
  const int b = blockIdx.x & 511;   // grid = 512*30
  const int d = blockIdx.x >> 9;

  // h1 [4][2048] during stages 1-2; h2 [8][1024] overlays it for stage 3.
  __shared__ float smem[8192 + 16];
  __shared__ float red[32];
  __shared__ float pooled[8];

  const int*    idrow = ids  + (size_t)b * 4096;
  const float*  mrow  = mask + (size_t)b * 4096;
  const float4* tbl4  = (const float4*)tbl;     // table row = 2x float4
  const float*  w1p = W1 + d * 96;
  const float*  w2p = W2 + d * 96;
  const float*  w3p = W3 + d * 192;

  // Zero never-written h1 tail slots + pad (determinism: no garbage reads).
  if (tid < 4)                  smem[tid * 2048 + 2047] = 0.0f;
  else if (tid >= 16 && tid < 32) smem[8192 + tid - 16] = 0.0f;

  // ---- stage 1: conv1 (E=8 -> 4ch, K=3, stride 2). 2 outputs/thread x 4 passes. ----
  {
    float bia[4];
    #pragma unroll
    for (int c = 0; c < 4; ++c) bia[c] = b1[d * 4 + c];

    #pragma unroll 1
    for (int pp = 0; pp < 4; ++pp) {
      const int l0 = pp * 512 + tid * 2;        // outputs l0, l0+1
      const int p0 = 2 * l0;                    // p0 = 4*tid + 1024*pp, 16B aligned
      const int4   iv = *(const int4*)(idrow + p0);
      const float4 mv = *(const float4*)(mrow + p0);
      int i4; float m4;
      if (p0 + 4 < 4096) { i4 = idrow[p0 + 4]; m4 = mrow[p0 + 4]; }
      else               { i4 = 0;              m4 = 0.0f; }

      const int   pid[5] = {iv.x, iv.y, iv.z, iv.w, i4};
      const float pm[5]  = {mv.x, mv.y, mv.z, mv.w, m4};
      float xv[5][8];
      #pragma unroll
      for (int q = 0; q < 5; ++q) {             // fully unrolled: const indices
        const float4 a = tbl4[(size_t)pid[q] * 2];
        const float4 c = tbl4[(size_t)pid[q] * 2 + 1];
        xv[q][0] = a.x * pm[q]; xv[q][1] = a.y * pm[q];
        xv[q][2] = a.z * pm[q]; xv[q][3] = a.w * pm[q];
        xv[q][4] = c.x * pm[q]; xv[q][5] = c.y * pm[q];
        xv[q][6] = c.z * pm[q]; xv[q][7] = c.w * pm[q];
      }

      float a0[4], a1[4];
      #pragma unroll
      for (int c = 0; c < 4; ++c) { a0[c] = bia[c]; a1[c] = bia[c]; }
      #pragma unroll
      for (int e = 0; e < 8; ++e) {             // FULLY unrolled (R3 lesson)
        #pragma unroll
        for (int c = 0; c < 4; ++c) {
          #pragma unroll
          for (int k = 0; k < 3; ++k) {
            const float w = w1p[c * 24 + e * 3 + k];   // uniform -> s_load
            a0[c] += xv[k][e]     * w;
            a1[c] += xv[2 + k][e] * w;
          }
        }
      }
      if (l0 + 1 < L1_) {        // lane-stride-8B float2 writes: conflict-free
        #pragma unroll
        for (int c = 0; c < 4; ++c)
          *(float2*)(smem + c * 2048 + l0) =
              make_float2(fmaxf(a0[c], 0.0f), fmaxf(a1[c], 0.0f));
      } else {                   // only pp==3, tid==255 (l0==2046)
        #pragma unroll
        for (int c = 0; c < 4; ++c)
          smem[c * 2048 + l0] = fmaxf(a0[c], 0.0f);
      }
    }
  }
  __syncthreads();

  // ---- stage 2: conv2 (4 -> 8ch, K=3, stride 2). pairs j0=2*tid+512g. ----
  float acc2[8][4];
  #pragma unroll
  for (int c2 = 0; c2 < 8; ++c2) {
    const float bb = b2[d * 8 + c2];
    #pragma unroll
    for (int q = 0; q < 4; ++q) acc2[c2][q] = bb;
  }
  #pragma unroll 1
  for (int c1 = 0; c1 < 4; ++c1) {              // 24 weight SGPRs live
    float sw[8][3];
    #pragma unroll
    for (int c2 = 0; c2 < 8; ++c2)
      #pragma unroll
      for (int kk = 0; kk < 3; ++kk)
        sw[c2][kk] = w2p[c2 * 12 + c1 * 3 + kk];   // uniform -> s_load
    #pragma unroll
    for (int g = 0; g < 2; ++g) {
      const int base = c1 * 2048 + 4 * tid + 1024 * g;   // 16B aligned
      const float4 h01 = *(const float4*)(smem + base);  // h[2j0 .. 2j0+3]
      const float  h4v = smem[base + 4];                 // h[2j0+4]
      #pragma unroll
      for (int c2 = 0; c2 < 8; ++c2) {
        acc2[c2][2 * g]     += h01.x * sw[c2][0] + h01.y * sw[c2][1] + h01.z * sw[c2][2];
        acc2[c2][2 * g + 1] += h01.z * sw[c2][0] + h01.w * sw[c2][1] + h4v   * sw[c2][2];
      }
    }
  }
  #pragma unroll
  for (int c2 = 0; c2 < 8; ++c2)
    #pragma unroll
    for (int q = 0; q < 4; ++q) acc2[c2][q] = fmaxf(acc2[c2][q], 0.0f);

  __syncthreads();               // all h1 reads done; overlay h2
  #pragma unroll
  for (int g = 0; g < 2; ++g) {
    const int j0 = 2 * tid + 512 * g;
    if (j0 + 1 < L2_) {          // lane-stride-8B float2: conflict-free
      #pragma unroll
      for (int c2 = 0; c2 < 8; ++c2)
        *(float2*)(smem + c2 * 1024 + j0) =
            make_float2(acc2[c2][2 * g], acc2[c2][2 * g + 1]);
    } else if (j0 < L2_) {       // tid==255, g==1 (j0==1022)
      #pragma unroll
      for (int c2 = 0; c2 < 8; ++c2)
        smem[c2 * 1024 + j0] = acc2[c2][2 * g];
    }
  }
  if (tid < 8) smem[tid * 1024 + 1023] = 0.0f;  // zero h2 tail slots
  __syncthreads();

  // ---- stage 3: conv3 (8 -> 8ch, K=3, stride 1) + relu + pool. pairs i0=2*tid+512g. ----
  float acc3[8][4];
  #pragma unroll
  for (int cc = 0; cc < 8; ++cc) {
    const float bb = b3[d * 8 + cc];
    #pragma unroll
    for (int q = 0; q < 4; ++q) acc3[cc][q] = bb;
  }
  #pragma unroll 1
  for (int c2 = 0; c2 < 8; ++c2) {              // 24 weight SGPRs live
    float sw[8][3];
    #pragma unroll
    for (int cc = 0; cc < 8; ++cc)
      #pragma unroll
      for (int kk = 0; kk < 3; ++kk)
        sw[cc][kk] = w3p[cc * 24 + c2 * 3 + kk];   // uniform -> s_load
    #pragma unroll
    for (int g = 0; g < 2; ++g) {
      const int base = c2 * 1024 + 2 * tid + 512 * g;    // 8B aligned
      const float2 ha = *(const float2*)(smem + base);       // h[i0], h[i0+1]
      const float2 hb = *(const float2*)(smem + base + 2);   // h[i0+2], h[i0+3]
      #pragma unroll
      for (int cc = 0; cc < 8; ++cc) {
        acc3[cc][2 * g]     += ha.x * sw[cc][0] + ha.y * sw[cc][1] + hb.x * sw[cc][2];
        acc3[cc][2 * g + 1] += ha.y * sw[cc][0] + hb.x * sw[cc][1] + hb.y * sw[cc][2];
      }
    }
  }
  float psum[8];
  #pragma unroll
  for (int cc = 0; cc < 8; ++cc) {
    float s = 0.0f;
    #pragma unroll
    for (int g = 0; g < 2; ++g) {
      const int i0 = 2 * tid + 512 * g;
      if (i0 < L3_)     s += fmaxf(acc3[cc][2 * g],     0.0f);
      if (i0 + 1 < L3_) s += fmaxf(acc3[cc][2 * g + 1], 0.0f);
    }
    psum[cc] = s;
  }

  // ---- block reduction of pooled sums ----
  const int lane = tid & 63;
  const int wid  = tid >> 6;
  #pragma unroll
  for (int c = 0; c < 8; ++c) {
    float v = psum[c];
    #pragma unroll
    for (int off = 32; off > 0; off >>= 1) v += __shfl_down(v, off, 64);
    if (lane == 0) red[wid * 8 + c] = v;
  }
  __syncthreads();
  if (tid < 8)
    pooled[tid] = red[tid] + red[8 + tid] + red[16 + tid] + red[24 + tid];
  __syncthreads();

  // ---- head: part[d][b][c] = z[d] * (mean(pooled) @ Wh^T + bh) ----
  if (tid < 10) {
    float acc = bh[d * 10 + tid];
    #pragma unroll
    for (int c3 = 0; c3 < 8; ++c3)
      acc += pooled[c3] * (1.0f / 1021.0f) * Wh[d * 80 + tid * 8 + c3];
    part[((size_t)d * 512 + b) * 10 + tid] = z[d] * acc;
  }
}

// Fixed-order reduction over d: bitwise-deterministic, overwrites d_out.
__global__ __launch_bounds__(256) void reduce_kernel(
    const float* __restrict__ part,   // [30][512][10]
    float* __restrict__ out)          // [512][10]
{
  const int i = blockIdx.x * 256 + threadIdx.x;   // 0..5119
  float s = 0.0f;
  #pragma unroll
  for (int dd = 0; dd < 30; ++dd) s += part[dd * 5120 + i];
  out[i] = s;
}

extern "C" void kernel_launch(void* const* d_in, const int* in_sizes, int n_in,
                              void* d_out, int out_size, void* d_ws, size_t ws_size,
                              hipStream_t stream) {
  const int*   ids  = (const int*)d_in[0];
  const float* mask = (const float*)d_in[1];
  const float* z    = (const float*)d_in[2];
  const float* tbl  = (const float*)d_in[3];
  const float* W1   = (const float*)d_in[4];
  const float* b1   = (const float*)d_in[5];
  const float* W2   = (const float*)d_in[6];
  const float* b2   = (const float*)d_in[7];
  const float* W3   = (const float*)d_in[8];
  const float* b3   = (const float*)d_in[9];
  const float* Wh   = (const float*)d_in[10];
  const float* bh   = (const float*)d_in[11];
  float* out  = (float*)d_out;
  float* part = (float*)d_ws;       // needs 30*512*10*4 = 614400 B

  hipLaunchKernelGGL(ensemble_kernel, dim3(512 * 30), dim3(256), 0, stream,
                     ids, mask, z, tbl, W1, b1, W2, b2, W3, b3, Wh, bh, part);
  hipLaunchKernelGGL(reduce_kernel, dim3(20), dim3(256), 0, stream, part, out);
}